// Round 1
// 584.077 us; speedup vs baseline: 1.0145x; 1.0145x over previous
//
#include <hip/hip_runtime.h>
#include <hip/hip_bf16.h>

#define T_TOK 4096
#define DM 1024
#define DF 2048
#define NE 8

typedef __attribute__((ext_vector_type(8))) short bf16x8;
typedef __attribute__((ext_vector_type(4))) float f32x4;

__device__ __forceinline__ unsigned short f2bf(float f) {
  union { float f; unsigned int i; } v; v.f = f;
  unsigned int r = v.i + 0x7fffu + ((v.i >> 16) & 1u);
  return (unsigned short)(r >> 16);
}

__device__ __forceinline__ float bf2f(unsigned short u) {
  union { unsigned int i; float f; } v; v.i = ((unsigned int)u) << 16;
  return v.f;
}

__device__ __forceinline__ uint4 pack8(float4 a, float4 b) {
  uint4 r;
  r.x = (unsigned int)f2bf(a.x) | ((unsigned int)f2bf(a.y) << 16);
  r.y = (unsigned int)f2bf(a.z) | ((unsigned int)f2bf(a.w) << 16);
  r.z = (unsigned int)f2bf(b.x) | ((unsigned int)f2bf(b.y) << 16);
  r.w = (unsigned int)f2bf(b.z) | ((unsigned int)f2bf(b.w) << 16);
  return r;
}

// async global->LDS, 16B per lane; LDS dest = wave-uniform base + lane*16
__device__ __forceinline__ void gl2lds(const unsigned short* g, unsigned short* l) {
  __builtin_amdgcn_global_load_lds(
      (const __attribute__((address_space(1))) unsigned int*)g,
      (__attribute__((address_space(3))) unsigned int*)l, 16, 0, 0);
}

// ---------------- fused fp32 -> bf16 conversion for X + all 6 weight tensors ----------------
__global__ void cvt_all_kernel(const float* __restrict__ X,
                               const float* __restrict__ swg, const float* __restrict__ swu,
                               const float* __restrict__ swd,
                               const float* __restrict__ ewg, const float* __restrict__ ewu,
                               const float* __restrict__ ewd,
                               unsigned short* __restrict__ Xbf,
                               unsigned short* __restrict__ Wg_sh, unsigned short* __restrict__ Wu_sh,
                               unsigned short* __restrict__ Wd_sh,
                               unsigned short* __restrict__ Wg_ex, unsigned short* __restrict__ Wu_ex,
                               unsigned short* __restrict__ Wd_ex) {
  int b = blockIdx.x;
  const float* src; unsigned short* dst; int base;
  if (b < 2048)        { src = X;   dst = Xbf;   base = 0; }
  else if (b < 3072)   { src = swg; dst = Wg_sh; base = 2048; }
  else if (b < 4096)   { src = swu; dst = Wu_sh; base = 3072; }
  else if (b < 5120)   { src = swd; dst = Wd_sh; base = 4096; }
  else if (b < 13312)  { src = ewg; dst = Wg_ex; base = 5120; }
  else if (b < 21504)  { src = ewu; dst = Wu_ex; base = 13312; }
  else                 { src = ewd; dst = Wd_ex; base = 21504; }
  size_t idx = (size_t)(b - base) * 256 + threadIdx.x;
  float4 a = ((const float4*)src)[2 * idx];
  float4 c = ((const float4*)src)[2 * idx + 1];
  ((uint4*)dst)[idx] = pack8(a, c);
}

// ---------------- router ----------------
__global__ void router_kernel(const float* __restrict__ X, const float* __restrict__ RW,
                              const float* __restrict__ bias, int* __restrict__ cnt,
                              int* __restrict__ lists, float* __restrict__ wpair) {
  int t = blockIdx.x * 4 + (threadIdx.x >> 6);
  int lane = threadIdx.x & 63;
  float xv[16];
#pragma unroll
  for (int j = 0; j < 16; j++) xv[j] = X[(size_t)t * DM + lane + 64 * j];
  float logit[NE];
#pragma unroll
  for (int e = 0; e < NE; e++) {
    float s = 0.f;
#pragma unroll
    for (int j = 0; j < 16; j++) s += xv[j] * RW[e * DM + lane + 64 * j];
#pragma unroll
    for (int off = 32; off > 0; off >>= 1) s += __shfl_xor(s, off);
    logit[e] = s + bias[e];
  }
  if (lane == 0) {
    float mx = logit[0];
#pragma unroll
    for (int e = 1; e < NE; e++) mx = fmaxf(mx, logit[e]);
    float p[NE]; float sum = 0.f;
#pragma unroll
    for (int e = 0; e < NE; e++) { p[e] = expf(logit[e] - mx); sum += p[e]; }
    float inv = 1.f / sum;
    int e0 = 0, e1 = -1; float p0 = -1.f, p1 = -1.f;
#pragma unroll
    for (int e = 0; e < NE; e++) {
      float pe = p[e] * inv;
      if (pe > p0) { p1 = p0; e1 = e0; p0 = pe; e0 = e; }
      else if (pe > p1) { p1 = pe; e1 = e; }
    }
    float q0 = expf(p0), q1 = expf(p1);
    float qs = q0 + q1;
    wpair[t * 2] = q0 / qs; wpair[t * 2 + 1] = q1 / qs;
    int pos0 = atomicAdd(&cnt[e0], 1);
    lists[e0 * T_TOK + pos0] = t * 2;
    int pos1 = atomicAdd(&cnt[e1], 1);
    lists[e1 * T_TOK + pos1] = t * 2 + 1;
  }
}

// Shared GEMM machinery: double-buffered LDS, stage-ahead (prefetch issued before the
// MFMA block; the compiler's vmcnt(0) drain before the end-of-step barrier then lands
// AFTER ~650cy of compute instead of immediately after issue). One barrier per K-step.
#define STAGE(K0, BUF) do { \
  _Pragma("unroll") \
  for (int d = 0; d < 8; d++) gl2lds(P[d] + (K0), L0[d] + (BUF) * 8192); \
} while (0)

#define COMPUTE(BUF) do { \
  const bf16x8* a0 = (const bf16x8*)(pA0 + (BUF) * 8192); \
  const bf16x8* a1 = (const bf16x8*)(pA1 + (BUF) * 8192); \
  const bf16x8* b0 = (const bf16x8*)(pB0 + (BUF) * 8192); \
  const bf16x8* b1 = (const bf16x8*)(pB1 + (BUF) * 8192); \
  bf16x8 af[4], bv[4]; \
  _Pragma("unroll") for (int mi = 0; mi < 4; mi++) af[mi] = a0[mi * 128]; \
  _Pragma("unroll") for (int ni = 0; ni < 4; ni++) bv[ni] = b0[ni * 128]; \
  _Pragma("unroll") for (int mi = 0; mi < 4; mi++) \
    _Pragma("unroll") for (int ni = 0; ni < 4; ni++) \
      acc[mi][ni] = __builtin_amdgcn_mfma_f32_16x16x32_bf16(af[mi], bv[ni], acc[mi][ni], 0, 0, 0); \
  _Pragma("unroll") for (int mi = 0; mi < 4; mi++) af[mi] = a1[mi * 128]; \
  _Pragma("unroll") for (int ni = 0; ni < 4; ni++) bv[ni] = b1[ni * 128]; \
  _Pragma("unroll") for (int mi = 0; mi < 4; mi++) \
    _Pragma("unroll") for (int ni = 0; ni < 4; ni++) \
      acc[mi][ni] = __builtin_amdgcn_mfma_f32_16x16x32_bf16(af[mi], bv[ni], acc[mi][ni], 0, 0, 0); \
} while (0)

// ---------------- gate+up GEMM: 128x128 GEMM tile = 128 tokens x 64 ff-cols of BOTH g,u ----
// B rows interleave gate/up per 16 (R>>4&1 selects matrix), so gate and up for the same
// ff-index land in adjacent n-frags of the same lane -> in-register silu pairing, no LDS
// exchange epilogue. Double-buffered staging with stage-ahead; 1 barrier per K-step.
__global__ __launch_bounds__(256, 2) void gateup_kernel(
    const unsigned short* __restrict__ Xbf,
    const unsigned short* __restrict__ Wg_sh, const unsigned short* __restrict__ Wu_sh,
    const unsigned short* __restrict__ Wg_ex, const unsigned short* __restrict__ Wu_ex,
    unsigned short* __restrict__ Hsh, unsigned short* __restrict__ Hpair,
    const int* __restrict__ lists, const int* __restrict__ cnt) {
  int z = blockIdx.z;
  bool gather = (z > 0);
  int e = z - 1;
  int M = gather ? cnt[e] : T_TOK;
  // XCD swizzle: XCD i (= lin%8) owns ff-tiles {4i..4i+3} -> weight tiles stay in its L2
  int lin = blockIdx.x + 32 * blockIdx.y;                 // 0..1023
  int m0 = (lin >> 5) * 128;
  int n0 = (4 * (lin & 7) + ((lin >> 3) & 3)) * 64;       // ff base, 64 ff per block
  if (m0 >= M) return;
  const unsigned short* Wg = gather ? Wg_ex + (size_t)e * DF * DM : Wg_sh;
  const unsigned short* Wu = gather ? Wu_ex + (size_t)e * DF * DM : Wu_sh;
  unsigned short* H = gather ? Hpair : Hsh;

  __shared__ unsigned short sA[2][128 * 64];   // 2 x 16 KB, [row][k] XOR-swizzled chunks
  __shared__ unsigned short sB[2][128 * 64];   // 2 x 16 KB, g/u interleaved per 16 rows
  __shared__ int sp[128];

  int tid = threadIdx.x;
  if (tid < 128) {
    int i = m0 + tid;
    sp[tid] = gather ? lists[e * T_TOK + min(i, M - 1)] : i;
  }
  __syncthreads();

  int lane = tid & 63, wv = tid >> 6;
  int rl = lane >> 3;                          // row within DMA (0..7)
  int swz = ((lane & 7) ^ rl) * 8;             // pre-swizzled global k offset (elems)
  const unsigned short* P[8];
  unsigned short* L0[8];
#pragma unroll
  for (int d = 0; d < 8; d++) {
    if (wv < 2) {
      int row = wv * 64 + 8 * d + rl;
      int t = sp[row];
      int xr = gather ? (t >> 1) : t;
      P[d] = Xbf + (size_t)xr * DM + swz;
      L0[d] = &sA[0][(wv * 64 + 8 * d) * 64];
    } else {
      int R = (wv - 2) * 64 + 8 * d + rl;      // B LDS row this lane feeds
      int mat = (R >> 4) & 1;                  // 0 = gate, 1 = up
      int sr = n0 + ((R >> 5) << 4) + (R & 15);
      P[d] = (mat ? Wu : Wg) + (size_t)sr * DM + swz;
      L0[d] = &sB[0][((wv - 2) * 64 + 8 * d) * 64];
    }
  }

  int wm = (wv >> 1) * 64, wn = (wv & 1) * 64;
  int quad = lane >> 4, l16 = lane & 15, r7 = l16 & 7;
  const unsigned short* pA0 = &sA[0][(wm + l16) * 64 + ((0 + quad) ^ r7) * 8];
  const unsigned short* pA1 = &sA[0][(wm + l16) * 64 + ((4 + quad) ^ r7) * 8];
  const unsigned short* pB0 = &sB[0][(wn + l16) * 64 + ((0 + quad) ^ r7) * 8];
  const unsigned short* pB1 = &sB[0][(wn + l16) * 64 + ((4 + quad) ^ r7) * 8];

  f32x4 acc[4][4];
  f32x4 zero = {0.f, 0.f, 0.f, 0.f};
#pragma unroll
  for (int i = 0; i < 4; i++)
#pragma unroll
    for (int j = 0; j < 4; j++) acc[i][j] = zero;

  STAGE(0, 0);
  __syncthreads();
  for (int k0 = 0; k0 < DM; k0 += 128) {
    STAGE(k0 + 64, 1);
    COMPUTE(0);
    __syncthreads();
    if (k0 + 128 < DM) STAGE(k0 + 128, 0);
    COMPUTE(1);
    __syncthreads();
  }

  // epilogue: gate = even n-frag, up = odd n-frag of same lane -> in-register silu
#pragma unroll
  for (int mi = 0; mi < 4; mi++)
#pragma unroll
    for (int nj = 0; nj < 4; nj += 2) {
      int ffb = ((wn + nj * 16) >> 5) * 16 + l16;   // ff col within block (0..63)
#pragma unroll
      for (int r = 0; r < 4; r++) {
        int row = wm + mi * 16 + quad * 4 + r;
        if (m0 + row < M) {
          float g = acc[mi][nj][r];
          float u = acc[mi][nj + 1][r];
          float h = (g / (1.f + __expf(-g))) * u;
          H[(size_t)sp[row] * DF + n0 + ffb] = f2bf(h);
        }
      }
    }
}

// ---------------- down GEMM: 128x128, double-buffered stage-ahead ----------------
__global__ __launch_bounds__(256, 2) void down_kernel(
    const unsigned short* __restrict__ Hsh, const unsigned short* __restrict__ Hpair,
    const unsigned short* __restrict__ Wd_sh, const unsigned short* __restrict__ Wd_ex,
    float* __restrict__ out, unsigned short* __restrict__ Opair,
    const int* __restrict__ lists, const int* __restrict__ cnt) {
  int z = blockIdx.z;
  bool gather = (z > 0);
  int e = z - 1;
  int M = gather ? cnt[e] : T_TOK;
  // XCD swizzle: XCD i owns n-tile i
  int lin = blockIdx.x + 32 * blockIdx.y;   // 0..255
  int m0 = (lin >> 3) * 128;
  int n0 = (lin & 7) * 128;
  if (m0 >= M) return;
  const unsigned short* Wd = gather ? Wd_ex + (size_t)e * DM * DF : Wd_sh;
  const unsigned short* Hbase = gather ? Hpair : Hsh;

  __shared__ unsigned short sA[2][128 * 64];   // 2 x 16 KB
  __shared__ unsigned short sB[2][128 * 64];   // 2 x 16 KB
  __shared__ int sp[128];

  int tid = threadIdx.x;
  if (tid < 128) {
    int i = m0 + tid;
    sp[tid] = gather ? lists[e * T_TOK + min(i, M - 1)] : i;
  }
  __syncthreads();

  int lane = tid & 63, wv = tid >> 6;
  int rl = lane >> 3;
  int swz = ((lane & 7) ^ rl) * 8;
  const unsigned short* P[8];
  unsigned short* L0[8];
#pragma unroll
  for (int d = 0; d < 8; d++) {
    if (wv < 2) {
      int row = wv * 64 + 8 * d + rl;
      P[d] = Hbase + (size_t)sp[row] * DF + swz;
      L0[d] = &sA[0][(wv * 64 + 8 * d) * 64];
    } else {
      int row = n0 + (wv - 2) * 64 + 8 * d + rl;
      P[d] = Wd + (size_t)row * DF + swz;
      L0[d] = &sB[0][((wv - 2) * 64 + 8 * d) * 64];
    }
  }

  int wm = (wv >> 1) * 64, wn = (wv & 1) * 64;
  int quad = lane >> 4, l16 = lane & 15, r7 = l16 & 7;
  const unsigned short* pA0 = &sA[0][(wm + l16) * 64 + ((0 + quad) ^ r7) * 8];
  const unsigned short* pA1 = &sA[0][(wm + l16) * 64 + ((4 + quad) ^ r7) * 8];
  const unsigned short* pB0 = &sB[0][(wn + l16) * 64 + ((0 + quad) ^ r7) * 8];
  const unsigned short* pB1 = &sB[0][(wn + l16) * 64 + ((4 + quad) ^ r7) * 8];

  f32x4 acc[4][4];
  f32x4 zero = {0.f, 0.f, 0.f, 0.f};
#pragma unroll
  for (int i = 0; i < 4; i++)
#pragma unroll
    for (int j = 0; j < 4; j++) acc[i][j] = zero;

  STAGE(0, 0);
  __syncthreads();
  for (int k0 = 0; k0 < DF; k0 += 128) {
    STAGE(k0 + 64, 1);
    COMPUTE(0);
    __syncthreads();
    if (k0 + 128 < DF) STAGE(k0 + 128, 0);
    COMPUTE(1);
    __syncthreads();
  }

#pragma unroll
  for (int mi = 0; mi < 4; mi++)
#pragma unroll
    for (int ni = 0; ni < 4; ni++)
#pragma unroll
      for (int r = 0; r < 4; r++) {
        int row = wm + mi * 16 + quad * 4 + r;
        if (m0 + row < M) {
          int col = n0 + wn + ni * 16 + l16;
          float v = acc[mi][ni][r];
          if (gather) {
            Opair[(size_t)sp[row] * DM + col] = f2bf(v);
          } else {
            out[(size_t)sp[row] * DM + col] = v;
          }
        }
      }
}

// ---------------- combine: out[t] += w0*Opair[2t] + w1*Opair[2t+1] ----------------
__global__ void combine_kernel(float* __restrict__ out, const unsigned short* __restrict__ Opair,
                               const float* __restrict__ wpair) {
  int idx = blockIdx.x * 256 + threadIdx.x;  // 8-element chunk
  int t = idx / (DM / 8);
  int c = (idx % (DM / 8)) * 8;
  float w0 = wpair[2 * t], w1 = wpair[2 * t + 1];
  const uint4* o0 = (const uint4*)(Opair + (size_t)(2 * t) * DM + c);
  const uint4* o1 = (const uint4*)(Opair + (size_t)(2 * t + 1) * DM + c);
  float4* op = (float4*)(out + (size_t)t * DM + c);
  uint4 a = o0[0], b = o1[0];
  float4 x0 = op[0], x1 = op[1];
  x0.x += w0 * bf2f(a.x & 0xffff)  + w1 * bf2f(b.x & 0xffff);
  x0.y += w0 * bf2f(a.x >> 16)     + w1 * bf2f(b.x >> 16);
  x0.z += w0 * bf2f(a.y & 0xffff)  + w1 * bf2f(b.y & 0xffff);
  x0.w += w0 * bf2f(a.y >> 16)     + w1 * bf2f(b.y >> 16);
  x1.x += w0 * bf2f(a.z & 0xffff)  + w1 * bf2f(b.z & 0xffff);
  x1.y += w0 * bf2f(a.z >> 16)     + w1 * bf2f(b.z >> 16);
  x1.z += w0 * bf2f(a.w & 0xffff)  + w1 * bf2f(b.w & 0xffff);
  x1.w += w0 * bf2f(a.w >> 16)     + w1 * bf2f(b.w >> 16);
  op[0] = x0; op[1] = x1;
}

extern "C" void kernel_launch(void* const* d_in, const int* in_sizes, int n_in,
                              void* d_out, int out_size, void* d_ws, size_t ws_size,
                              hipStream_t stream) {
  const float* X       = (const float*)d_in[0];
  const float* RW      = (const float*)d_in[1];
  const float* bias    = (const float*)d_in[2];
  const float* sw_gate = (const float*)d_in[3];
  const float* sw_up   = (const float*)d_in[4];
  const float* sw_down = (const float*)d_in[5];
  const float* ew_gate = (const float*)d_in[6];
  const float* ew_up   = (const float*)d_in[7];
  const float* ew_down = (const float*)d_in[8];
  float* out = (float*)d_out;

  char* ws = (char*)d_ws;
  const size_t MB = 1 << 20;
  unsigned short* Xbf   = (unsigned short*)(ws);              //   8 MB
  unsigned short* Hsh   = (unsigned short*)(ws + 8 * MB);     //  16 MB
  unsigned short* Hpair = (unsigned short*)(ws + 24 * MB);    //  32 MB
  unsigned short* Wg_sh = (unsigned short*)(ws + 56 * MB);    //   4 MB
  unsigned short* Wu_sh = (unsigned short*)(ws + 60 * MB);    //   4 MB
  unsigned short* Wd_sh = (unsigned short*)(ws + 64 * MB);    //   4 MB
  unsigned short* Wg_ex = (unsigned short*)(ws + 68 * MB);    //  32 MB
  unsigned short* Wu_ex = (unsigned short*)(ws + 100 * MB);   //  32 MB
  unsigned short* Wd_ex = (unsigned short*)(ws + 132 * MB);   //  32 MB
  unsigned short* Opair = (unsigned short*)(ws + 164 * MB);   //  16 MB
  int*   lists = (int*)(ws + 180 * MB);                       // 128 KB
  float* wpair = (float*)(ws + 180 * MB + (128 << 10));       //  32 KB
  int*   cnt   = (int*)(ws + 180 * MB + (160 << 10));         //  32 B

  hipMemsetAsync(cnt, 0, NE * sizeof(int), stream);
  cvt_all_kernel<<<29696, 256, 0, stream>>>(X, sw_gate, sw_up, sw_down, ew_gate, ew_up, ew_down,
                                            Xbf, Wg_sh, Wu_sh, Wd_sh, Wg_ex, Wu_ex, Wd_ex);
  router_kernel<<<T_TOK / 4, 256, 0, stream>>>(X, RW, bias, cnt, lists, wpair);
  gateup_kernel<<<dim3(32, 32, NE + 1), 256, 0, stream>>>(
      Xbf, Wg_sh, Wu_sh, Wg_ex, Wu_ex, Hsh, Hpair, lists, cnt);
  down_kernel<<<dim3(32, 8, NE + 1), 256, 0, stream>>>(
      Hsh, Hpair, Wd_sh, Wd_ex, out, Opair, lists, cnt);
  combine_kernel<<<T_TOK * DM / 8 / 256, 256, 0, stream>>>(out, Opair, wpair);
}

// Round 2
// 566.363 us; speedup vs baseline: 1.0462x; 1.0313x over previous
//
#include <hip/hip_runtime.h>
#include <hip/hip_bf16.h>

#define T_TOK 4096
#define DM 1024
#define DF 2048
#define NE 8

typedef __attribute__((ext_vector_type(8))) short bf16x8;
typedef __attribute__((ext_vector_type(4))) float f32x4;

__device__ __forceinline__ unsigned short f2bf(float f) {
  union { float f; unsigned int i; } v; v.f = f;
  unsigned int r = v.i + 0x7fffu + ((v.i >> 16) & 1u);
  return (unsigned short)(r >> 16);
}

__device__ __forceinline__ float bf2f(unsigned short u) {
  union { unsigned int i; float f; } v; v.i = ((unsigned int)u) << 16;
  return v.f;
}

__device__ __forceinline__ uint4 pack8(float4 a, float4 b) {
  uint4 r;
  r.x = (unsigned int)f2bf(a.x) | ((unsigned int)f2bf(a.y) << 16);
  r.y = (unsigned int)f2bf(a.z) | ((unsigned int)f2bf(a.w) << 16);
  r.z = (unsigned int)f2bf(b.x) | ((unsigned int)f2bf(b.y) << 16);
  r.w = (unsigned int)f2bf(b.z) | ((unsigned int)f2bf(b.w) << 16);
  return r;
}

// async global->LDS, 16B per lane; LDS dest = wave-uniform base + lane*16
__device__ __forceinline__ void gl2lds(const unsigned short* g, unsigned short* l) {
  __builtin_amdgcn_global_load_lds(
      (const __attribute__((address_space(1))) unsigned int*)g,
      (__attribute__((address_space(3))) unsigned int*)l, 16, 0, 0);
}

// ---------------- fused fp32 -> bf16 conversion for X + all 6 weight tensors ----------------
__global__ void cvt_all_kernel(const float* __restrict__ X,
                               const float* __restrict__ swg, const float* __restrict__ swu,
                               const float* __restrict__ swd,
                               const float* __restrict__ ewg, const float* __restrict__ ewu,
                               const float* __restrict__ ewd,
                               unsigned short* __restrict__ Xbf,
                               unsigned short* __restrict__ Wg_sh, unsigned short* __restrict__ Wu_sh,
                               unsigned short* __restrict__ Wd_sh,
                               unsigned short* __restrict__ Wg_ex, unsigned short* __restrict__ Wu_ex,
                               unsigned short* __restrict__ Wd_ex) {
  int b = blockIdx.x;
  const float* src; unsigned short* dst; int base;
  if (b < 2048)        { src = X;   dst = Xbf;   base = 0; }
  else if (b < 3072)   { src = swg; dst = Wg_sh; base = 2048; }
  else if (b < 4096)   { src = swu; dst = Wu_sh; base = 3072; }
  else if (b < 5120)   { src = swd; dst = Wd_sh; base = 4096; }
  else if (b < 13312)  { src = ewg; dst = Wg_ex; base = 5120; }
  else if (b < 21504)  { src = ewu; dst = Wu_ex; base = 13312; }
  else                 { src = ewd; dst = Wd_ex; base = 21504; }
  size_t idx = (size_t)(b - base) * 256 + threadIdx.x;
  float4 a = ((const float4*)src)[2 * idx];
  float4 c = ((const float4*)src)[2 * idx + 1];
  ((uint4*)dst)[idx] = pack8(a, c);
}

// ---------------- router ----------------
__global__ void router_kernel(const float* __restrict__ X, const float* __restrict__ RW,
                              const float* __restrict__ bias, int* __restrict__ cnt,
                              int* __restrict__ lists, float* __restrict__ wpair) {
  int t = blockIdx.x * 4 + (threadIdx.x >> 6);
  int lane = threadIdx.x & 63;
  float xv[16];
#pragma unroll
  for (int j = 0; j < 16; j++) xv[j] = X[(size_t)t * DM + lane + 64 * j];
  float logit[NE];
#pragma unroll
  for (int e = 0; e < NE; e++) {
    float s = 0.f;
#pragma unroll
    for (int j = 0; j < 16; j++) s += xv[j] * RW[e * DM + lane + 64 * j];
#pragma unroll
    for (int off = 32; off > 0; off >>= 1) s += __shfl_xor(s, off);
    logit[e] = s + bias[e];
  }
  if (lane == 0) {
    float mx = logit[0];
#pragma unroll
    for (int e = 1; e < NE; e++) mx = fmaxf(mx, logit[e]);
    float p[NE]; float sum = 0.f;
#pragma unroll
    for (int e = 0; e < NE; e++) { p[e] = expf(logit[e] - mx); sum += p[e]; }
    float inv = 1.f / sum;
    int e0 = 0, e1 = -1; float p0 = -1.f, p1 = -1.f;
#pragma unroll
    for (int e = 0; e < NE; e++) {
      float pe = p[e] * inv;
      if (pe > p0) { p1 = p0; e1 = e0; p0 = pe; e0 = e; }
      else if (pe > p1) { p1 = pe; e1 = e; }
    }
    float q0 = expf(p0), q1 = expf(p1);
    float qs = q0 + q1;
    wpair[t * 2] = q0 / qs; wpair[t * 2 + 1] = q1 / qs;
    int pos0 = atomicAdd(&cnt[e0], 1);
    lists[e0 * T_TOK + pos0] = t * 2;
    int pos1 = atomicAdd(&cnt[e1], 1);
    lists[e1 * T_TOK + pos1] = t * 2 + 1;
  }
}

// ---- GEMM K-loop machinery: double-buffered LDS, T4 counted vmcnt (never drain to 0 in
// steady state), raw s_barrier, T5 setprio around MFMA. Each wave issues exactly 8
// global_load_lds per STAGE, so vmcnt(8) == "my previous STAGE has landed"; the barrier
// after it makes that true for ALL waves' loads. WAR: a plain barrier separates
// "everyone done reading buf" from the re-issue into buf.
#define SBAR   __builtin_amdgcn_s_barrier()
#define VMCNT8 asm volatile("s_waitcnt vmcnt(8)" ::: "memory")
#define VMCNT0 asm volatile("s_waitcnt vmcnt(0)" ::: "memory")

#define STAGE(K0, BUF) do { \
  _Pragma("unroll") \
  for (int d = 0; d < 8; d++) gl2lds(P[d] + (K0), L0[d] + (BUF) * 8192); \
} while (0)

#define COMPUTE(BUF) do { \
  const bf16x8* a0 = (const bf16x8*)(pA0 + (BUF) * 8192); \
  const bf16x8* a1 = (const bf16x8*)(pA1 + (BUF) * 8192); \
  const bf16x8* b0 = (const bf16x8*)(pB0 + (BUF) * 8192); \
  const bf16x8* b1 = (const bf16x8*)(pB1 + (BUF) * 8192); \
  bf16x8 af[4], bv[4]; \
  _Pragma("unroll") for (int mi = 0; mi < 4; mi++) af[mi] = a0[mi * 128]; \
  _Pragma("unroll") for (int ni = 0; ni < 4; ni++) bv[ni] = b0[ni * 128]; \
  __builtin_amdgcn_s_setprio(1); \
  _Pragma("unroll") for (int mi = 0; mi < 4; mi++) \
    _Pragma("unroll") for (int ni = 0; ni < 4; ni++) \
      acc[mi][ni] = __builtin_amdgcn_mfma_f32_16x16x32_bf16(af[mi], bv[ni], acc[mi][ni], 0, 0, 0); \
  __builtin_amdgcn_s_setprio(0); \
  _Pragma("unroll") for (int mi = 0; mi < 4; mi++) af[mi] = a1[mi * 128]; \
  _Pragma("unroll") for (int ni = 0; ni < 4; ni++) bv[ni] = b1[ni * 128]; \
  __builtin_amdgcn_s_setprio(1); \
  _Pragma("unroll") for (int mi = 0; mi < 4; mi++) \
    _Pragma("unroll") for (int ni = 0; ni < 4; ni++) \
      acc[mi][ni] = __builtin_amdgcn_mfma_f32_16x16x32_bf16(af[mi], bv[ni], acc[mi][ni], 0, 0, 0); \
  __builtin_amdgcn_s_setprio(0); \
} while (0)

// K-loop: prologue stages both buffers; steady state keeps one STAGE (8 loads) in flight
// across each barrier; tail drains with vmcnt(0) only once.
#define KLOOP(KDIM) do { \
  STAGE(0, 0); \
  STAGE(64, 1); \
  VMCNT8; SBAR; \
  for (int k0 = 0; k0 < (KDIM) - 128; k0 += 128) { \
    COMPUTE(0); \
    SBAR; \
    STAGE(k0 + 128, 0); \
    VMCNT8; SBAR; \
    COMPUTE(1); \
    SBAR; \
    STAGE(k0 + 192, 1); \
    VMCNT8; SBAR; \
  } \
  COMPUTE(0); \
  VMCNT0; SBAR; \
  COMPUTE(1); \
} while (0)

// ---------------- gate+up GEMM: 128x128 GEMM tile = 128 tokens x 64 ff-cols of BOTH g,u ----
// B rows interleave gate/up per 16 (R>>4&1 selects matrix), so gate and up for the same
// ff-index land in adjacent n-frags of the same lane -> in-register silu pairing.
__global__ __launch_bounds__(256, 2) void gateup_kernel(
    const unsigned short* __restrict__ Xbf,
    const unsigned short* __restrict__ Wg_sh, const unsigned short* __restrict__ Wu_sh,
    const unsigned short* __restrict__ Wg_ex, const unsigned short* __restrict__ Wu_ex,
    unsigned short* __restrict__ Hsh, unsigned short* __restrict__ Hpair,
    const int* __restrict__ lists, const int* __restrict__ cnt) {
  int z = blockIdx.z;
  bool gather = (z > 0);
  int e = z - 1;
  int M = gather ? cnt[e] : T_TOK;
  // XCD swizzle: XCD i (= lin%8) owns ff-tiles {4i..4i+3} -> weight tiles stay in its L2
  int lin = blockIdx.x + 32 * blockIdx.y;                 // 0..1023
  int m0 = (lin >> 5) * 128;
  int n0 = (4 * (lin & 7) + ((lin >> 3) & 3)) * 64;       // ff base, 64 ff per block
  if (m0 >= M) return;
  const unsigned short* Wg = gather ? Wg_ex + (size_t)e * DF * DM : Wg_sh;
  const unsigned short* Wu = gather ? Wu_ex + (size_t)e * DF * DM : Wu_sh;
  unsigned short* H = gather ? Hpair : Hsh;

  __shared__ unsigned short sA[2][128 * 64];   // 2 x 16 KB, [row][k] XOR-swizzled chunks
  __shared__ unsigned short sB[2][128 * 64];   // 2 x 16 KB, g/u interleaved per 16 rows
  __shared__ int sp[128];

  int tid = threadIdx.x;
  if (tid < 128) {
    int i = m0 + tid;
    sp[tid] = gather ? lists[e * T_TOK + min(i, M - 1)] : i;
  }
  __syncthreads();   // also drains the sp[] global loads -> vmcnt==0 entering KLOOP

  int lane = tid & 63, wv = tid >> 6;
  int rl = lane >> 3;                          // row within DMA (0..7)
  int swz = ((lane & 7) ^ rl) * 8;             // pre-swizzled global k offset (elems)
  const unsigned short* P[8];
  unsigned short* L0[8];
#pragma unroll
  for (int d = 0; d < 8; d++) {
    if (wv < 2) {
      int row = wv * 64 + 8 * d + rl;
      int t = sp[row];
      int xr = gather ? (t >> 1) : t;
      P[d] = Xbf + (size_t)xr * DM + swz;
      L0[d] = &sA[0][(wv * 64 + 8 * d) * 64];
    } else {
      int R = (wv - 2) * 64 + 8 * d + rl;      // B LDS row this lane feeds
      int mat = (R >> 4) & 1;                  // 0 = gate, 1 = up
      int sr = n0 + ((R >> 5) << 4) + (R & 15);
      P[d] = (mat ? Wu : Wg) + (size_t)sr * DM + swz;
      L0[d] = &sB[0][((wv - 2) * 64 + 8 * d) * 64];
    }
  }

  int wm = (wv >> 1) * 64, wn = (wv & 1) * 64;
  int quad = lane >> 4, l16 = lane & 15, r7 = l16 & 7;
  const unsigned short* pA0 = &sA[0][(wm + l16) * 64 + ((0 + quad) ^ r7) * 8];
  const unsigned short* pA1 = &sA[0][(wm + l16) * 64 + ((4 + quad) ^ r7) * 8];
  const unsigned short* pB0 = &sB[0][(wn + l16) * 64 + ((0 + quad) ^ r7) * 8];
  const unsigned short* pB1 = &sB[0][(wn + l16) * 64 + ((4 + quad) ^ r7) * 8];

  f32x4 acc[4][4];
  f32x4 zero = {0.f, 0.f, 0.f, 0.f};
#pragma unroll
  for (int i = 0; i < 4; i++)
#pragma unroll
    for (int j = 0; j < 4; j++) acc[i][j] = zero;

  KLOOP(DM);

  // epilogue: gate = even n-frag, up = odd n-frag of same lane -> in-register silu
#pragma unroll
  for (int mi = 0; mi < 4; mi++)
#pragma unroll
    for (int nj = 0; nj < 4; nj += 2) {
      int ffb = ((wn + nj * 16) >> 5) * 16 + l16;   // ff col within block (0..63)
#pragma unroll
      for (int r = 0; r < 4; r++) {
        int row = wm + mi * 16 + quad * 4 + r;
        if (m0 + row < M) {
          float g = acc[mi][nj][r];
          float u = acc[mi][nj + 1][r];
          float h = (g / (1.f + __expf(-g))) * u;
          H[(size_t)sp[row] * DF + n0 + ffb] = f2bf(h);
        }
      }
    }
}

// ---------------- down GEMM: 128x128, double-buffered, counted-vmcnt pipeline ----------------
__global__ __launch_bounds__(256, 2) void down_kernel(
    const unsigned short* __restrict__ Hsh, const unsigned short* __restrict__ Hpair,
    const unsigned short* __restrict__ Wd_sh, const unsigned short* __restrict__ Wd_ex,
    float* __restrict__ out, unsigned short* __restrict__ Opair,
    const int* __restrict__ lists, const int* __restrict__ cnt) {
  int z = blockIdx.z;
  bool gather = (z > 0);
  int e = z - 1;
  int M = gather ? cnt[e] : T_TOK;
  // XCD swizzle: XCD i owns n-tile i
  int lin = blockIdx.x + 32 * blockIdx.y;   // 0..255
  int m0 = (lin >> 3) * 128;
  int n0 = (lin & 7) * 128;
  if (m0 >= M) return;
  const unsigned short* Wd = gather ? Wd_ex + (size_t)e * DM * DF : Wd_sh;
  const unsigned short* Hbase = gather ? Hpair : Hsh;

  __shared__ unsigned short sA[2][128 * 64];   // 2 x 16 KB
  __shared__ unsigned short sB[2][128 * 64];   // 2 x 16 KB
  __shared__ int sp[128];

  int tid = threadIdx.x;
  if (tid < 128) {
    int i = m0 + tid;
    sp[tid] = gather ? lists[e * T_TOK + min(i, M - 1)] : i;
  }
  __syncthreads();

  int lane = tid & 63, wv = tid >> 6;
  int rl = lane >> 3;
  int swz = ((lane & 7) ^ rl) * 8;
  const unsigned short* P[8];
  unsigned short* L0[8];
#pragma unroll
  for (int d = 0; d < 8; d++) {
    if (wv < 2) {
      int row = wv * 64 + 8 * d + rl;
      P[d] = Hbase + (size_t)sp[row] * DF + swz;
      L0[d] = &sA[0][(wv * 64 + 8 * d) * 64];
    } else {
      int row = n0 + (wv - 2) * 64 + 8 * d + rl;
      P[d] = Wd + (size_t)row * DF + swz;
      L0[d] = &sB[0][((wv - 2) * 64 + 8 * d) * 64];
    }
  }

  int wm = (wv >> 1) * 64, wn = (wv & 1) * 64;
  int quad = lane >> 4, l16 = lane & 15, r7 = l16 & 7;
  const unsigned short* pA0 = &sA[0][(wm + l16) * 64 + ((0 + quad) ^ r7) * 8];
  const unsigned short* pA1 = &sA[0][(wm + l16) * 64 + ((4 + quad) ^ r7) * 8];
  const unsigned short* pB0 = &sB[0][(wn + l16) * 64 + ((0 + quad) ^ r7) * 8];
  const unsigned short* pB1 = &sB[0][(wn + l16) * 64 + ((4 + quad) ^ r7) * 8];

  f32x4 acc[4][4];
  f32x4 zero = {0.f, 0.f, 0.f, 0.f};
#pragma unroll
  for (int i = 0; i < 4; i++)
#pragma unroll
    for (int j = 0; j < 4; j++) acc[i][j] = zero;

  KLOOP(DF);

#pragma unroll
  for (int mi = 0; mi < 4; mi++)
#pragma unroll
    for (int ni = 0; ni < 4; ni++)
#pragma unroll
      for (int r = 0; r < 4; r++) {
        int row = wm + mi * 16 + quad * 4 + r;
        if (m0 + row < M) {
          int col = n0 + wn + ni * 16 + l16;
          float v = acc[mi][ni][r];
          if (gather) {
            Opair[(size_t)sp[row] * DM + col] = f2bf(v);
          } else {
            out[(size_t)sp[row] * DM + col] = v;
          }
        }
      }
}

// ---------------- combine: out[t] += w0*Opair[2t] + w1*Opair[2t+1] ----------------
__global__ void combine_kernel(float* __restrict__ out, const unsigned short* __restrict__ Opair,
                               const float* __restrict__ wpair) {
  int idx = blockIdx.x * 256 + threadIdx.x;  // 8-element chunk
  int t = idx / (DM / 8);
  int c = (idx % (DM / 8)) * 8;
  float w0 = wpair[2 * t], w1 = wpair[2 * t + 1];
  const uint4* o0 = (const uint4*)(Opair + (size_t)(2 * t) * DM + c);
  const uint4* o1 = (const uint4*)(Opair + (size_t)(2 * t + 1) * DM + c);
  float4* op = (float4*)(out + (size_t)t * DM + c);
  uint4 a = o0[0], b = o1[0];
  float4 x0 = op[0], x1 = op[1];
  x0.x += w0 * bf2f(a.x & 0xffff)  + w1 * bf2f(b.x & 0xffff);
  x0.y += w0 * bf2f(a.x >> 16)     + w1 * bf2f(b.x >> 16);
  x0.z += w0 * bf2f(a.y & 0xffff)  + w1 * bf2f(b.y & 0xffff);
  x0.w += w0 * bf2f(a.y >> 16)     + w1 * bf2f(b.y >> 16);
  x1.x += w0 * bf2f(a.z & 0xffff)  + w1 * bf2f(b.z & 0xffff);
  x1.y += w0 * bf2f(a.z >> 16)     + w1 * bf2f(b.z >> 16);
  x1.z += w0 * bf2f(a.w & 0xffff)  + w1 * bf2f(b.w & 0xffff);
  x1.w += w0 * bf2f(a.w >> 16)     + w1 * bf2f(b.w >> 16);
  op[0] = x0; op[1] = x1;
}

extern "C" void kernel_launch(void* const* d_in, const int* in_sizes, int n_in,
                              void* d_out, int out_size, void* d_ws, size_t ws_size,
                              hipStream_t stream) {
  const float* X       = (const float*)d_in[0];
  const float* RW      = (const float*)d_in[1];
  const float* bias    = (const float*)d_in[2];
  const float* sw_gate = (const float*)d_in[3];
  const float* sw_up   = (const float*)d_in[4];
  const float* sw_down = (const float*)d_in[5];
  const float* ew_gate = (const float*)d_in[6];
  const float* ew_up   = (const float*)d_in[7];
  const float* ew_down = (const float*)d_in[8];
  float* out = (float*)d_out;

  char* ws = (char*)d_ws;
  const size_t MB = 1 << 20;
  unsigned short* Xbf   = (unsigned short*)(ws);              //   8 MB
  unsigned short* Hsh   = (unsigned short*)(ws + 8 * MB);     //  16 MB
  unsigned short* Hpair = (unsigned short*)(ws + 24 * MB);    //  32 MB
  unsigned short* Wg_sh = (unsigned short*)(ws + 56 * MB);    //   4 MB
  unsigned short* Wu_sh = (unsigned short*)(ws + 60 * MB);    //   4 MB
  unsigned short* Wd_sh = (unsigned short*)(ws + 64 * MB);    //   4 MB
  unsigned short* Wg_ex = (unsigned short*)(ws + 68 * MB);    //  32 MB
  unsigned short* Wu_ex = (unsigned short*)(ws + 100 * MB);   //  32 MB
  unsigned short* Wd_ex = (unsigned short*)(ws + 132 * MB);   //  32 MB
  unsigned short* Opair = (unsigned short*)(ws + 164 * MB);   //  16 MB
  int*   lists = (int*)(ws + 180 * MB);                       // 128 KB
  float* wpair = (float*)(ws + 180 * MB + (128 << 10));       //  32 KB
  int*   cnt   = (int*)(ws + 180 * MB + (160 << 10));         //  32 B

  hipMemsetAsync(cnt, 0, NE * sizeof(int), stream);
  cvt_all_kernel<<<29696, 256, 0, stream>>>(X, sw_gate, sw_up, sw_down, ew_gate, ew_up, ew_down,
                                            Xbf, Wg_sh, Wu_sh, Wd_sh, Wg_ex, Wu_ex, Wd_ex);
  router_kernel<<<T_TOK / 4, 256, 0, stream>>>(X, RW, bias, cnt, lists, wpair);
  gateup_kernel<<<dim3(32, 32, NE + 1), 256, 0, stream>>>(
      Xbf, Wg_sh, Wu_sh, Wg_ex, Wu_ex, Hsh, Hpair, lists, cnt);
  down_kernel<<<dim3(32, 8, NE + 1), 256, 0, stream>>>(
      Hsh, Hpair, Wd_sh, Wd_ex, out, Opair, lists, cnt);
  combine_kernel<<<T_TOK * DM / 8 / 256, 256, 0, stream>>>(out, Opair, wpair);
}

// Round 3
// 557.902 us; speedup vs baseline: 1.0621x; 1.0152x over previous
//
#include <hip/hip_runtime.h>
#include <hip/hip_bf16.h>

#define T_TOK 4096
#define DM 1024
#define DF 2048
#define NE 8

typedef __attribute__((ext_vector_type(8))) short bf16x8;
typedef __attribute__((ext_vector_type(4))) float f32x4;

__device__ __forceinline__ unsigned short f2bf(float f) {
  union { float f; unsigned int i; } v; v.f = f;
  unsigned int r = v.i + 0x7fffu + ((v.i >> 16) & 1u);
  return (unsigned short)(r >> 16);
}

__device__ __forceinline__ float bf2f(unsigned short u) {
  union { unsigned int i; float f; } v; v.i = ((unsigned int)u) << 16;
  return v.f;
}

__device__ __forceinline__ uint4 pack8(float4 a, float4 b) {
  uint4 r;
  r.x = (unsigned int)f2bf(a.x) | ((unsigned int)f2bf(a.y) << 16);
  r.y = (unsigned int)f2bf(a.z) | ((unsigned int)f2bf(a.w) << 16);
  r.z = (unsigned int)f2bf(b.x) | ((unsigned int)f2bf(b.y) << 16);
  r.w = (unsigned int)f2bf(b.z) | ((unsigned int)f2bf(b.w) << 16);
  return r;
}

// async global->LDS, 16B per lane; LDS dest = wave-uniform base + lane*16
__device__ __forceinline__ void gl2lds(const unsigned short* g, unsigned short* l) {
  __builtin_amdgcn_global_load_lds(
      (const __attribute__((address_space(1))) unsigned int*)g,
      (__attribute__((address_space(3))) unsigned int*)l, 16, 0, 0);
}

// ---------------- fused fp32 -> bf16 conversion for X + all 6 weight tensors ----------------
__global__ void cvt_all_kernel(const float* __restrict__ X,
                               const float* __restrict__ swg, const float* __restrict__ swu,
                               const float* __restrict__ swd,
                               const float* __restrict__ ewg, const float* __restrict__ ewu,
                               const float* __restrict__ ewd,
                               unsigned short* __restrict__ Xbf,
                               unsigned short* __restrict__ Wg_sh, unsigned short* __restrict__ Wu_sh,
                               unsigned short* __restrict__ Wd_sh,
                               unsigned short* __restrict__ Wg_ex, unsigned short* __restrict__ Wu_ex,
                               unsigned short* __restrict__ Wd_ex) {
  int b = blockIdx.x;
  const float* src; unsigned short* dst; int base;
  if (b < 2048)        { src = X;   dst = Xbf;   base = 0; }
  else if (b < 3072)   { src = swg; dst = Wg_sh; base = 2048; }
  else if (b < 4096)   { src = swu; dst = Wu_sh; base = 3072; }
  else if (b < 5120)   { src = swd; dst = Wd_sh; base = 4096; }
  else if (b < 13312)  { src = ewg; dst = Wg_ex; base = 5120; }
  else if (b < 21504)  { src = ewu; dst = Wu_ex; base = 13312; }
  else                 { src = ewd; dst = Wd_ex; base = 21504; }
  size_t idx = (size_t)(b - base) * 256 + threadIdx.x;
  float4 a = ((const float4*)src)[2 * idx];
  float4 c = ((const float4*)src)[2 * idx + 1];
  ((uint4*)dst)[idx] = pack8(a, c);
}

// ---------------- router ----------------
__global__ void router_kernel(const float* __restrict__ X, const float* __restrict__ RW,
                              const float* __restrict__ bias, int* __restrict__ cnt,
                              int* __restrict__ lists, float* __restrict__ wpair) {
  int t = blockIdx.x * 4 + (threadIdx.x >> 6);
  int lane = threadIdx.x & 63;
  float xv[16];
#pragma unroll
  for (int j = 0; j < 16; j++) xv[j] = X[(size_t)t * DM + lane + 64 * j];
  float logit[NE];
#pragma unroll
  for (int e = 0; e < NE; e++) {
    float s = 0.f;
#pragma unroll
    for (int j = 0; j < 16; j++) s += xv[j] * RW[e * DM + lane + 64 * j];
#pragma unroll
    for (int off = 32; off > 0; off >>= 1) s += __shfl_xor(s, off);
    logit[e] = s + bias[e];
  }
  if (lane == 0) {
    float mx = logit[0];
#pragma unroll
    for (int e = 1; e < NE; e++) mx = fmaxf(mx, logit[e]);
    float p[NE]; float sum = 0.f;
#pragma unroll
    for (int e = 0; e < NE; e++) { p[e] = expf(logit[e] - mx); sum += p[e]; }
    float inv = 1.f / sum;
    int e0 = 0, e1 = -1; float p0 = -1.f, p1 = -1.f;
#pragma unroll
    for (int e = 0; e < NE; e++) {
      float pe = p[e] * inv;
      if (pe > p0) { p1 = p0; e1 = e0; p0 = pe; e0 = e; }
      else if (pe > p1) { p1 = pe; e1 = e; }
    }
    float q0 = expf(p0), q1 = expf(p1);
    float qs = q0 + q1;
    wpair[t * 2] = q0 / qs; wpair[t * 2 + 1] = q1 / qs;
    int pos0 = atomicAdd(&cnt[e0], 1);
    lists[e0 * T_TOK + pos0] = t * 2;
    int pos1 = atomicAdd(&cnt[e1], 1);
    lists[e1 * T_TOK + pos1] = t * 2 + 1;
  }
}

// ---- GEMM K-loop: 8 waves/block (512 thr), double-buffered LDS, counted vmcnt (T4),
// raw s_barrier, setprio around MFMA (T5). Each wave issues exactly 4 global_load_lds
// per STAGE, so vmcnt(4) == "my previous STAGE has landed"; the barrier after it makes
// that true for all waves. Per-wave output 64x32 (acc[4][2]) -> 4 waves/SIMD at
// 2 blocks/CU for latency cover (TLP), halved per-wave ds_read+MFMA per phase.
#define SBAR   __builtin_amdgcn_s_barrier()
#define VMCNT4 asm volatile("s_waitcnt vmcnt(4)" ::: "memory")
#define VMCNT0 asm volatile("s_waitcnt vmcnt(0)" ::: "memory")

#define STAGE(K0, BUF) do { \
  _Pragma("unroll") \
  for (int d = 0; d < 4; d++) gl2lds(P[d] + (K0), L0[d] + (BUF) * 8192); \
} while (0)

#define COMPUTE(BUF) do { \
  const bf16x8* a0 = (const bf16x8*)(pA0 + (BUF) * 8192); \
  const bf16x8* a1 = (const bf16x8*)(pA1 + (BUF) * 8192); \
  const bf16x8* b0 = (const bf16x8*)(pB0 + (BUF) * 8192); \
  const bf16x8* b1 = (const bf16x8*)(pB1 + (BUF) * 8192); \
  bf16x8 af[4], bv[2]; \
  _Pragma("unroll") for (int mi = 0; mi < 4; mi++) af[mi] = a0[mi * 128]; \
  _Pragma("unroll") for (int ni = 0; ni < 2; ni++) bv[ni] = b0[ni * 128]; \
  __builtin_amdgcn_s_setprio(1); \
  _Pragma("unroll") for (int mi = 0; mi < 4; mi++) \
    _Pragma("unroll") for (int ni = 0; ni < 2; ni++) \
      acc[mi][ni] = __builtin_amdgcn_mfma_f32_16x16x32_bf16(af[mi], bv[ni], acc[mi][ni], 0, 0, 0); \
  __builtin_amdgcn_s_setprio(0); \
  _Pragma("unroll") for (int mi = 0; mi < 4; mi++) af[mi] = a1[mi * 128]; \
  _Pragma("unroll") for (int ni = 0; ni < 2; ni++) bv[ni] = b1[ni * 128]; \
  __builtin_amdgcn_s_setprio(1); \
  _Pragma("unroll") for (int mi = 0; mi < 4; mi++) \
    _Pragma("unroll") for (int ni = 0; ni < 2; ni++) \
      acc[mi][ni] = __builtin_amdgcn_mfma_f32_16x16x32_bf16(af[mi], bv[ni], acc[mi][ni], 0, 0, 0); \
  __builtin_amdgcn_s_setprio(0); \
} while (0)

// K-loop: prologue stages both buffers; steady state keeps one STAGE (4 loads) in flight
// across each barrier; tail drains with vmcnt(0) only once.
#define KLOOP(KDIM) do { \
  STAGE(0, 0); \
  STAGE(64, 1); \
  VMCNT4; SBAR; \
  for (int k0 = 0; k0 < (KDIM) - 128; k0 += 128) { \
    COMPUTE(0); \
    SBAR; \
    STAGE(k0 + 128, 0); \
    VMCNT4; SBAR; \
    COMPUTE(1); \
    SBAR; \
    STAGE(k0 + 192, 1); \
    VMCNT4; SBAR; \
  } \
  COMPUTE(0); \
  VMCNT0; SBAR; \
  COMPUTE(1); \
} while (0)

// ---------------- gate+up GEMM: 128x128 GEMM tile = 128 tokens x 64 ff-cols of BOTH g,u ----
// B rows interleave gate/up per 16 (R>>4&1 selects matrix), so gate and up for the same
// ff-index land in the two n-frags of the same wave -> in-register silu pairing.
__global__ __launch_bounds__(512, 4) void gateup_kernel(
    const unsigned short* __restrict__ Xbf,
    const unsigned short* __restrict__ Wg_sh, const unsigned short* __restrict__ Wu_sh,
    const unsigned short* __restrict__ Wg_ex, const unsigned short* __restrict__ Wu_ex,
    unsigned short* __restrict__ Hsh, unsigned short* __restrict__ Hpair,
    const int* __restrict__ lists, const int* __restrict__ cnt) {
  int z = blockIdx.z;
  bool gather = (z > 0);
  int e = z - 1;
  int M = gather ? cnt[e] : T_TOK;
  // XCD swizzle: XCD i (= lin%8) owns ff-tiles {4i..4i+3} -> weight tiles stay in its L2
  int lin = blockIdx.x + 32 * blockIdx.y;                 // 0..1023
  int m0 = (lin >> 5) * 128;
  int n0 = (4 * (lin & 7) + ((lin >> 3) & 3)) * 64;       // ff base, 64 ff per block
  if (m0 >= M) return;
  const unsigned short* Wg = gather ? Wg_ex + (size_t)e * DF * DM : Wg_sh;
  const unsigned short* Wu = gather ? Wu_ex + (size_t)e * DF * DM : Wu_sh;
  unsigned short* H = gather ? Hpair : Hsh;

  __shared__ unsigned short sA[2][128 * 64];   // 2 x 16 KB, [row][k] XOR-swizzled chunks
  __shared__ unsigned short sB[2][128 * 64];   // 2 x 16 KB, g/u interleaved per 16 rows
  __shared__ int sp[128];

  int tid = threadIdx.x;
  if (tid < 128) {
    int i = m0 + tid;
    sp[tid] = gather ? lists[e * T_TOK + min(i, M - 1)] : i;
  }
  __syncthreads();   // drains sp[] loads -> per-wave vmcnt==0 entering KLOOP

  int lane = tid & 63, wv = tid >> 6;          // wv 0..7
  int rl = lane >> 3;                          // row within DMA (0..7)
  int swz = ((lane & 7) ^ rl) * 8;             // pre-swizzled global k offset (elems)
  const unsigned short* P[4];
  unsigned short* L0[4];
#pragma unroll
  for (int d = 0; d < 4; d++) {
    if (wv < 4) {
      int g = wv * 4 + d;                      // A row-group 0..15
      int row = 8 * g + rl;
      int t = sp[row];
      int xr = gather ? (t >> 1) : t;
      P[d] = Xbf + (size_t)xr * DM + swz;
      L0[d] = &sA[0][(8 * g) * 64];
    } else {
      int g = (wv - 4) * 4 + d;                // B row-group 0..15
      int R = 8 * g + rl;                      // B LDS row this lane feeds
      int mat = (R >> 4) & 1;                  // 0 = gate, 1 = up
      int sr = n0 + ((R >> 5) << 4) + (R & 15);
      P[d] = (mat ? Wu : Wg) + (size_t)sr * DM + swz;
      L0[d] = &sB[0][(8 * g) * 64];
    }
  }

  int wm = (wv >> 2) * 64, wn = (wv & 3) * 32;
  int quad = lane >> 4, l16 = lane & 15, r7 = l16 & 7;
  const unsigned short* pA0 = &sA[0][(wm + l16) * 64 + ((0 + quad) ^ r7) * 8];
  const unsigned short* pA1 = &sA[0][(wm + l16) * 64 + ((4 + quad) ^ r7) * 8];
  const unsigned short* pB0 = &sB[0][(wn + l16) * 64 + ((0 + quad) ^ r7) * 8];
  const unsigned short* pB1 = &sB[0][(wn + l16) * 64 + ((4 + quad) ^ r7) * 8];

  f32x4 acc[4][2];
  f32x4 zero = {0.f, 0.f, 0.f, 0.f};
#pragma unroll
  for (int i = 0; i < 4; i++)
#pragma unroll
    for (int j = 0; j < 2; j++) acc[i][j] = zero;

  KLOOP(DM);

  // epilogue: n-frag 0 = gate, n-frag 1 = up (same 16 ffs) -> in-register silu
  int ffb = (wn >> 5) * 16 + l16;              // ff col within block (0..63)
#pragma unroll
  for (int mi = 0; mi < 4; mi++)
#pragma unroll
    for (int r = 0; r < 4; r++) {
      int row = wm + mi * 16 + quad * 4 + r;
      if (m0 + row < M) {
        float g = acc[mi][0][r];
        float u = acc[mi][1][r];
        float h = (g / (1.f + __expf(-g))) * u;
        H[(size_t)sp[row] * DF + n0 + ffb] = f2bf(h);
      }
    }
}

// ---------------- down GEMM: 128x128, 8-wave, double-buffered, counted-vmcnt --------------
__global__ __launch_bounds__(512, 4) void down_kernel(
    const unsigned short* __restrict__ Hsh, const unsigned short* __restrict__ Hpair,
    const unsigned short* __restrict__ Wd_sh, const unsigned short* __restrict__ Wd_ex,
    float* __restrict__ out, unsigned short* __restrict__ Opair,
    const int* __restrict__ lists, const int* __restrict__ cnt) {
  int z = blockIdx.z;
  bool gather = (z > 0);
  int e = z - 1;
  int M = gather ? cnt[e] : T_TOK;
  // XCD swizzle: XCD i owns n-tile i
  int lin = blockIdx.x + 32 * blockIdx.y;   // 0..255
  int m0 = (lin >> 3) * 128;
  int n0 = (lin & 7) * 128;
  if (m0 >= M) return;
  const unsigned short* Wd = gather ? Wd_ex + (size_t)e * DM * DF : Wd_sh;
  const unsigned short* Hbase = gather ? Hpair : Hsh;

  __shared__ unsigned short sA[2][128 * 64];   // 2 x 16 KB
  __shared__ unsigned short sB[2][128 * 64];   // 2 x 16 KB
  __shared__ int sp[128];

  int tid = threadIdx.x;
  if (tid < 128) {
    int i = m0 + tid;
    sp[tid] = gather ? lists[e * T_TOK + min(i, M - 1)] : i;
  }
  __syncthreads();

  int lane = tid & 63, wv = tid >> 6;
  int rl = lane >> 3;
  int swz = ((lane & 7) ^ rl) * 8;
  const unsigned short* P[4];
  unsigned short* L0[4];
#pragma unroll
  for (int d = 0; d < 4; d++) {
    if (wv < 4) {
      int g = wv * 4 + d;
      int row = 8 * g + rl;
      P[d] = Hbase + (size_t)sp[row] * DF + swz;
      L0[d] = &sA[0][(8 * g) * 64];
    } else {
      int g = (wv - 4) * 4 + d;
      int row = n0 + 8 * g + rl;
      P[d] = Wd + (size_t)row * DF + swz;
      L0[d] = &sB[0][(8 * g) * 64];
    }
  }

  int wm = (wv >> 2) * 64, wn = (wv & 3) * 32;
  int quad = lane >> 4, l16 = lane & 15, r7 = l16 & 7;
  const unsigned short* pA0 = &sA[0][(wm + l16) * 64 + ((0 + quad) ^ r7) * 8];
  const unsigned short* pA1 = &sA[0][(wm + l16) * 64 + ((4 + quad) ^ r7) * 8];
  const unsigned short* pB0 = &sB[0][(wn + l16) * 64 + ((0 + quad) ^ r7) * 8];
  const unsigned short* pB1 = &sB[0][(wn + l16) * 64 + ((4 + quad) ^ r7) * 8];

  f32x4 acc[4][2];
  f32x4 zero = {0.f, 0.f, 0.f, 0.f};
#pragma unroll
  for (int i = 0; i < 4; i++)
#pragma unroll
    for (int j = 0; j < 2; j++) acc[i][j] = zero;

  KLOOP(DF);

#pragma unroll
  for (int mi = 0; mi < 4; mi++)
#pragma unroll
    for (int ni = 0; ni < 2; ni++)
#pragma unroll
      for (int r = 0; r < 4; r++) {
        int row = wm + mi * 16 + quad * 4 + r;
        if (m0 + row < M) {
          int col = n0 + wn + ni * 16 + l16;
          float v = acc[mi][ni][r];
          if (gather) {
            Opair[(size_t)sp[row] * DM + col] = f2bf(v);
          } else {
            out[(size_t)sp[row] * DM + col] = v;
          }
        }
      }
}

// ---------------- combine: out[t] += w0*Opair[2t] + w1*Opair[2t+1] ----------------
__global__ void combine_kernel(float* __restrict__ out, const unsigned short* __restrict__ Opair,
                               const float* __restrict__ wpair) {
  int idx = blockIdx.x * 256 + threadIdx.x;  // 8-element chunk
  int t = idx / (DM / 8);
  int c = (idx % (DM / 8)) * 8;
  float w0 = wpair[2 * t], w1 = wpair[2 * t + 1];
  const uint4* o0 = (const uint4*)(Opair + (size_t)(2 * t) * DM + c);
  const uint4* o1 = (const uint4*)(Opair + (size_t)(2 * t + 1) * DM + c);
  float4* op = (float4*)(out + (size_t)t * DM + c);
  uint4 a = o0[0], b = o1[0];
  float4 x0 = op[0], x1 = op[1];
  x0.x += w0 * bf2f(a.x & 0xffff)  + w1 * bf2f(b.x & 0xffff);
  x0.y += w0 * bf2f(a.x >> 16)     + w1 * bf2f(b.x >> 16);
  x0.z += w0 * bf2f(a.y & 0xffff)  + w1 * bf2f(b.y & 0xffff);
  x0.w += w0 * bf2f(a.y >> 16)     + w1 * bf2f(b.y >> 16);
  x1.x += w0 * bf2f(a.z & 0xffff)  + w1 * bf2f(b.z & 0xffff);
  x1.y += w0 * bf2f(a.z >> 16)     + w1 * bf2f(b.z >> 16);
  x1.z += w0 * bf2f(a.w & 0xffff)  + w1 * bf2f(b.w & 0xffff);
  x1.w += w0 * bf2f(a.w >> 16)     + w1 * bf2f(b.w >> 16);
  op[0] = x0; op[1] = x1;
}

extern "C" void kernel_launch(void* const* d_in, const int* in_sizes, int n_in,
                              void* d_out, int out_size, void* d_ws, size_t ws_size,
                              hipStream_t stream) {
  const float* X       = (const float*)d_in[0];
  const float* RW      = (const float*)d_in[1];
  const float* bias    = (const float*)d_in[2];
  const float* sw_gate = (const float*)d_in[3];
  const float* sw_up   = (const float*)d_in[4];
  const float* sw_down = (const float*)d_in[5];
  const float* ew_gate = (const float*)d_in[6];
  const float* ew_up   = (const float*)d_in[7];
  const float* ew_down = (const float*)d_in[8];
  float* out = (float*)d_out;

  char* ws = (char*)d_ws;
  const size_t MB = 1 << 20;
  unsigned short* Xbf   = (unsigned short*)(ws);              //   8 MB
  unsigned short* Hsh   = (unsigned short*)(ws + 8 * MB);     //  16 MB
  unsigned short* Hpair = (unsigned short*)(ws + 24 * MB);    //  32 MB
  unsigned short* Wg_sh = (unsigned short*)(ws + 56 * MB);    //   4 MB
  unsigned short* Wu_sh = (unsigned short*)(ws + 60 * MB);    //   4 MB
  unsigned short* Wd_sh = (unsigned short*)(ws + 64 * MB);    //   4 MB
  unsigned short* Wg_ex = (unsigned short*)(ws + 68 * MB);    //  32 MB
  unsigned short* Wu_ex = (unsigned short*)(ws + 100 * MB);   //  32 MB
  unsigned short* Wd_ex = (unsigned short*)(ws + 132 * MB);   //  32 MB
  unsigned short* Opair = (unsigned short*)(ws + 164 * MB);   //  16 MB
  int*   lists = (int*)(ws + 180 * MB);                       // 128 KB
  float* wpair = (float*)(ws + 180 * MB + (128 << 10));       //  32 KB
  int*   cnt   = (int*)(ws + 180 * MB + (160 << 10));         //  32 B

  hipMemsetAsync(cnt, 0, NE * sizeof(int), stream);
  cvt_all_kernel<<<29696, 256, 0, stream>>>(X, sw_gate, sw_up, sw_down, ew_gate, ew_up, ew_down,
                                            Xbf, Wg_sh, Wu_sh, Wd_sh, Wg_ex, Wu_ex, Wd_ex);
  router_kernel<<<T_TOK / 4, 256, 0, stream>>>(X, RW, bias, cnt, lists, wpair);
  gateup_kernel<<<dim3(32, 32, NE + 1), 512, 0, stream>>>(
      Xbf, Wg_sh, Wu_sh, Wg_ex, Wu_ex, Hsh, Hpair, lists, cnt);
  down_kernel<<<dim3(32, 8, NE + 1), 512, 0, stream>>>(
      Hsh, Hpair, Wd_sh, Wd_ex, out, Opair, lists, cnt);
  combine_kernel<<<T_TOK * DM / 8 / 256, 256, 0, stream>>>(out, Opair, wpair);
}